// Round 1
// baseline (18502.620 us; speedup 1.0000x reference)
//
#include <hip/hip_runtime.h>
#include <hip/hip_bf16.h>
#include <math.h>

#define B_ 64
#define T_ 1024
#define D_ 512
#define H_ 512
#define M_ 256
#define CC 63
#define SS 64
#define INV_SQRT_2PI 0.3989422804014327f

static __device__ __forceinline__ float bf2f(unsigned short u) {
    unsigned int x = ((unsigned int)u) << 16;
    return __uint_as_float(x);
}
static __device__ __forceinline__ unsigned short f2bf(float f) {
    unsigned int x = __float_as_uint(f);
    unsigned int r = (x + 0x7fff + ((x >> 16) & 1)) >> 16;
    return (unsigned short)r;
}
static __device__ __forceinline__ float sigm(float x) {
    return 1.f / (1.f + __expf(-x));
}

// ---------------- prologue kernels ----------------

// zero states, ctxT[d][b] = L[b][0][d]
__global__ __launch_bounds__(256) void k_init(const float* __restrict__ Lf,
        float* __restrict__ h0A, float* __restrict__ h0B, float* __restrict__ c0,
        float* __restrict__ h1A, float* __restrict__ h1B, float* __restrict__ c1,
        float* __restrict__ ctxT) {
    int idx = blockIdx.x * 256 + threadIdx.x;
    if (idx < H_ * B_) {
        h0A[idx] = 0.f; h0B[idx] = 0.f; c0[idx] = 0.f;
        h1A[idx] = 0.f; h1B[idx] = 0.f; c1[idx] = 0.f;
        int d = idx >> 6, b = idx & 63;
        ctxT[idx] = Lf[(size_t)b * (T_ * D_) + d];
    }
}

// gtT[s][k][b] = gt[b][s][k]   (63 k's per s)
__global__ __launch_bounds__(256) void k_gtt(const float* __restrict__ gt,
        float* __restrict__ gtT) {
    int s = blockIdx.x;
    for (int r = threadIdx.x; r < CC * 64; r += 256) {
        int kk = r >> 6, b = r & 63;
        gtT[s * (CC * 64) + r] = gt[(b * SS + s) * CC + kk];
    }
}

// listener f32 -> bf16
__global__ __launch_bounds__(256) void k_conv(const float* __restrict__ Lf,
        unsigned short* __restrict__ Lbf, int n4) {
    int stride = gridDim.x * 256;
    for (int i = blockIdx.x * 256 + threadIdx.x; i < n4; i += stride) {
        float4 v = ((const float4*)Lf)[i];
        ushort4 o;
        o.x = f2bf(v.x); o.y = f2bf(v.y); o.z = f2bf(v.z); o.w = f2bf(v.w);
        ((ushort4*)Lbf)[i] = o;
    }
}

// clT[b][m][t] = bf16(relu(sum_d L[b][t][d]*psi[m][d] + psib[m]))
__global__ __launch_bounds__(256) void k_gemm(const float* __restrict__ Lf,
        const float* __restrict__ psiw, const float* __restrict__ psib,
        unsigned short* __restrict__ clT) {
    __shared__ float At[64 * 65];
    __shared__ float Bt[64 * 65];
    int tid = threadIdx.x;
    int pt = blockIdx.x >> 2;
    int mt = blockIdx.x & 3;
    int p0 = pt * 64, m0 = mt * 64;
    int tp = tid >> 4, tm = tid & 15;
    float acc[4][4] = {{0.f}};
    for (int k0 = 0; k0 < 512; k0 += 64) {
        __syncthreads();
        for (int i = 0; i < 16; ++i) {
            int lidx = i * 256 + tid;
            int r = lidx >> 6, c = lidx & 63;
            At[r * 65 + c] = Lf[(size_t)(p0 + r) * 512 + k0 + c];
            Bt[r * 65 + c] = psiw[(size_t)(m0 + r) * 512 + k0 + c];
        }
        __syncthreads();
        for (int dk = 0; dk < 64; ++dk) {
            float av[4], bv[4];
#pragma unroll
            for (int i = 0; i < 4; ++i) av[i] = At[(4 * tp + i) * 65 + dk];
#pragma unroll
            for (int j = 0; j < 4; ++j) bv[j] = Bt[(4 * tm + j) * 65 + dk];
#pragma unroll
            for (int i = 0; i < 4; ++i)
#pragma unroll
                for (int j = 0; j < 4; ++j)
                    acc[i][j] = fmaf(av[i], bv[j], acc[i][j]);
        }
    }
#pragma unroll
    for (int i = 0; i < 4; ++i) {
        int p = p0 + 4 * tp + i;
        int b = p >> 10, t = p & 1023;
#pragma unroll
        for (int j = 0; j < 4; ++j) {
            int m = m0 + 4 * tm + j;
            float v = fmaxf(acc[i][j] + psib[m], 0.f);
            clT[((size_t)(b * 256 + m)) * 1024 + t] = f2bf(v);
        }
    }
}

// ---------------- per-step kernels ----------------

// LSTM0 (blocks < 256) + char-pred for step ps (blocks >= 256 when mode==1; all when mode==2)
__global__ __launch_bounds__(256) void k_dec(
        int mode, int s, int ps,
        const float* __restrict__ gtT,
        const float* __restrict__ wih0, const float* __restrict__ whh0,
        const float* __restrict__ bih0, const float* __restrict__ bhh0,
        const float* __restrict__ charw, const float* __restrict__ charb,
        const float* __restrict__ h0_in, float* __restrict__ h0_out,
        float* __restrict__ c0,
        const float* __restrict__ h1_prev, const float* __restrict__ ctxT,
        float* __restrict__ preds_out) {
    __shared__ float sm[64 * 64 + 512];
    int tid = threadIdx.x;
    int bidx = blockIdx.x;
    bool predBlock = (mode == 2) || (mode == 1 && bidx >= 256);
    if (!predBlock) {
        int u0 = bidx * 2;
        int b = tid & 63;
        int g = tid >> 6;
        int j0 = g * 512 + u0;
        float acc0 = bih0[j0] + bhh0[j0];
        float acc1 = bih0[j0 + 1] + bhh0[j0 + 1];
        const float* w0r = wih0 + (size_t)j0 * 575;
        const float* w1r = wih0 + (size_t)(j0 + 1) * 575;
        const float* v0r = whh0 + (size_t)j0 * 512;
        const float* v1r = whh0 + (size_t)(j0 + 1) * 512;
        for (int k0 = 0; k0 < 1088; k0 += 64) {
            __syncthreads();
            for (int i = 0; i < 16; ++i) {
                int lidx = i * 256 + tid;
                int k = k0 + (lidx >> 6);
                int bb = lidx & 63;
                float v;
                if (k < 63) {
                    v = (s > 0) ? gtT[(s - 1) * (CC * 64) + lidx]
                                : ((k == 0) ? 1.f : 0.f);
                } else if (k < 575) {
                    v = ctxT[(k - 63) * 64 + bb];
                } else if (k < 1087) {
                    v = h0_in[(k - 575) * 64 + bb];
                } else v = 0.f;
                sm[lidx] = v;
            }
            __syncthreads();
            for (int kk = 0; kk < 64; ++kk) {
                int k = k0 + kk;
                float xv = sm[kk * 64 + b];
                float w0, w1;
                if (k < 575)      { w0 = w0r[k];        w1 = w1r[k]; }
                else if (k < 1087){ w0 = v0r[k - 575];  w1 = v1r[k - 575]; }
                else              { w0 = 0.f;           w1 = 0.f; }
                acc0 = fmaf(xv, w0, acc0);
                acc1 = fmaf(xv, w1, acc1);
            }
        }
        float* ex = sm + 4096;
        __syncthreads();
        ex[(g * 2 + 0) * 64 + b] = acc0;
        ex[(g * 2 + 1) * 64 + b] = acc1;
        __syncthreads();
        if (tid < 128) {
            int b2 = tid & 63;
            int i = tid >> 6;
            int u = u0 + i;
            float gi = ex[(0 * 2 + i) * 64 + b2];
            float gf = ex[(1 * 2 + i) * 64 + b2];
            float gg = ex[(2 * 2 + i) * 64 + b2];
            float go = ex[(3 * 2 + i) * 64 + b2];
            float cv = c0[u * 64 + b2];
            float cn = sigm(gf) * cv + sigm(gi) * tanhf(gg);
            float hn = sigm(go) * tanhf(cn);
            c0[u * 64 + b2] = cn;
            h0_out[u * 64 + b2] = hn;
        }
    } else {
        int b = (mode == 2) ? bidx : (bidx - 256);
        for (int i = 0; i < 4; ++i) {
            int u = i * 256 + tid;
            sm[u] = (u < 512) ? h1_prev[u * 64 + b] : ctxT[(u - 512) * 64 + b];
        }
        __syncthreads();
        if (tid < 64) {
            int c = tid;
            float logit = -1e30f;
            if (c < 63) {
                float a = charb[c];
                const float4* wr = (const float4*)(charw + (size_t)c * 1024);
                for (int u4 = 0; u4 < 256; ++u4) {
                    float4 w4 = wr[u4];
                    a = fmaf(sm[4 * u4 + 0], w4.x, a);
                    a = fmaf(sm[4 * u4 + 1], w4.y, a);
                    a = fmaf(sm[4 * u4 + 2], w4.z, a);
                    a = fmaf(sm[4 * u4 + 3], w4.w, a);
                }
                logit = a;
            }
            float mx = logit;
            for (int o = 32; o > 0; o >>= 1) mx = fmaxf(mx, __shfl_xor(mx, o, 64));
            float ex2 = (c < 63) ? __expf(logit - mx) : 0.f;
            float sum = ex2;
            for (int o = 32; o > 0; o >>= 1) sum += __shfl_xor(sum, o, 64);
            if (c < 63)
                preds_out[((size_t)ps * B_ + b) * CC + c] = logit - mx - __logf(sum);
        }
    }
}

__global__ __launch_bounds__(256) void k_lstm1(
        const float* __restrict__ wih1, const float* __restrict__ whh1,
        const float* __restrict__ bih1, const float* __restrict__ bhh1,
        const float* __restrict__ h0new, const float* __restrict__ h1_in,
        float* __restrict__ h1_out, float* __restrict__ c1) {
    __shared__ float sm[64 * 64 + 512];
    int tid = threadIdx.x;
    int u0 = blockIdx.x * 2;
    int b = tid & 63, g = tid >> 6;
    int j0 = g * 512 + u0;
    float acc0 = bih1[j0] + bhh1[j0];
    float acc1 = bih1[j0 + 1] + bhh1[j0 + 1];
    const float* w0r = wih1 + (size_t)j0 * 512;
    const float* w1r = wih1 + (size_t)(j0 + 1) * 512;
    const float* v0r = whh1 + (size_t)j0 * 512;
    const float* v1r = whh1 + (size_t)(j0 + 1) * 512;
    for (int k0 = 0; k0 < 1024; k0 += 64) {
        __syncthreads();
        for (int i = 0; i < 16; ++i) {
            int lidx = i * 256 + tid;
            int k = k0 + (lidx >> 6);
            int bb = lidx & 63;
            sm[lidx] = (k < 512) ? h0new[k * 64 + bb] : h1_in[(k - 512) * 64 + bb];
        }
        __syncthreads();
        for (int kk = 0; kk < 64; ++kk) {
            int k = k0 + kk;
            float xv = sm[kk * 64 + b];
            float w0, w1;
            if (k < 512) { w0 = w0r[k];       w1 = w1r[k]; }
            else         { w0 = v0r[k - 512]; w1 = v1r[k - 512]; }
            acc0 = fmaf(xv, w0, acc0);
            acc1 = fmaf(xv, w1, acc1);
        }
    }
    float* ex = sm + 4096;
    __syncthreads();
    ex[(g * 2 + 0) * 64 + b] = acc0;
    ex[(g * 2 + 1) * 64 + b] = acc1;
    __syncthreads();
    if (tid < 128) {
        int b2 = tid & 63;
        int i = tid >> 6;
        int u = u0 + i;
        float gi = ex[(0 * 2 + i) * 64 + b2];
        float gf = ex[(1 * 2 + i) * 64 + b2];
        float gg = ex[(2 * 2 + i) * 64 + b2];
        float go = ex[(3 * 2 + i) * 64 + b2];
        float cv = c1[u * 64 + b2];
        float cn = sigm(gf) * cv + sigm(gi) * tanhf(gg);
        float hn = sigm(go) * tanhf(cn);
        c1[u * 64 + b2] = cn;
        h1_out[u * 64 + b2] = hn;
    }
}

// comp_dec (redundant per block) + energy row-chunk
__global__ __launch_bounds__(256) void k_energy(
        const float* __restrict__ phiw, const float* __restrict__ phib,
        const float* __restrict__ h1, const unsigned short* __restrict__ clT,
        float* __restrict__ energy) {
    __shared__ float xs[512];
    __shared__ float cd[256];
    int tid = threadIdx.x;
    int b = blockIdx.x >> 1;
    int t0 = (blockIdx.x & 1) * 512;
    xs[tid] = h1[tid * 64 + b];
    xs[tid + 256] = h1[(tid + 256) * 64 + b];
    __syncthreads();
    {
        int m = tid;
        float a = phib[m];
        const float4* wr = (const float4*)(phiw + (size_t)m * 512);
        for (int u4 = 0; u4 < 128; ++u4) {
            float4 w4 = wr[u4];
            a = fmaf(xs[4 * u4 + 0], w4.x, a);
            a = fmaf(xs[4 * u4 + 1], w4.y, a);
            a = fmaf(xs[4 * u4 + 2], w4.z, a);
            a = fmaf(xs[4 * u4 + 3], w4.w, a);
        }
        cd[m] = fmaxf(a, 0.f);
    }
    __syncthreads();
    int tt = t0 + 2 * tid;
    float e0 = 0.f, e1 = 0.f;
    const unsigned short* base = clT + ((size_t)b * 256) * 1024 + tt;
#pragma unroll 4
    for (int m = 0; m < 256; ++m) {
        unsigned int v = *(const unsigned int*)(base + (size_t)m * 1024);
        float c = cd[m];
        e0 = fmaf(c, bf2f((unsigned short)(v & 0xffff)), e0);
        e1 = fmaf(c, bf2f((unsigned short)(v >> 16)), e1);
    }
    *(float2*)(energy + b * 1024 + tt) = make_float2(e0, e1);
}

// copula stats + softmax -> atts[s]
__global__ __launch_bounds__(256) void k_att(
        int s, const float* __restrict__ energy, float* __restrict__ atts_out) {
    __shared__ float rowE[1024];
    __shared__ float meanV[1024];
    __shared__ float rL[1024];
    __shared__ float dsL[1024];
    __shared__ unsigned char badL[1024];
    __shared__ float red[256];
    __shared__ int zflag;
    int tid = threadIdx.x;
    int b = blockIdx.x;
    if (tid == 0) zflag = 0;
    for (int i = 0; i < 4; ++i) {
        int t = tid + 256 * i;
        rowE[t] = energy[b * 1024 + t];
    }
    __syncthreads();
    // column means over batch + zero-column check
    for (int i = 0; i < 4; ++i) {
        int t = tid + 256 * i;
        float ssum = 0.f; bool zc = true;
#pragma unroll 4
        for (int bb = 0; bb < 64; ++bb) {
            float v = energy[bb * 1024 + t];
            ssum += v; zc = zc && (v == 0.f);
        }
        meanV[t] = ssum * (1.f / 64.f);
        if (zc) atomicOr(&zflag, 1);
    }
    __syncthreads();
    // correlation stats per coppdf column ct in [1,1023)
    for (int i = 0; i < 4; ++i) {
        int ct = 1 + tid + 256 * i;
        if (ct < 1023) {
            float ma = meanV[ct - 1], mb = meanV[ct];
            float sab = 0.f, saa = 0.f, sbb = 0.f; bool aeq = true;
#pragma unroll 4
            for (int bb = 0; bb < 64; ++bb) {
                float a = energy[bb * 1024 + ct - 1];
                float b2 = energy[bb * 1024 + ct];
                float am = a - ma, bm = b2 - mb;
                sab = fmaf(am, bm, sab);
                saa = fmaf(am, am, saa);
                sbb = fmaf(bm, bm, sbb);
                aeq = aeq && (a == b2);
            }
            float r = sab / sqrtf(saa * sbb + 1e-12f);
            float det = 1.f - r * r;
            badL[ct] = ((det < 0.01f) || aeq) ? 1 : 0;
            rL[ct] = r;
            dsL[ct] = fmaxf(det, 1e-6f);
        }
    }
    __syncthreads();
    int zf = zflag;
    float vals[4];
    for (int i = 0; i < 4; ++i) {
        int t = tid + 256 * i;
        float e = rowE[t];
        float v;
        if (zf) {
            v = e;
        } else {
            float pdf = __expf(-0.5f * e * e) * INV_SQRT_2PI;
            float cp;
            if (t == 0 || t == 1023) cp = 1.f;
            else if (badL[t]) cp = 10.f;
            else {
                float a = rowE[t - 1];
                float r = rL[t], ds = dsL[t];
                float quad = r * r * (a * a + e * e) - 2.f * r * a * e;
                cp = __expf(-0.5f * quad / ds) / sqrtf(ds);
            }
            v = pdf * cp;
        }
        vals[i] = v;
    }
    float mx = fmaxf(fmaxf(vals[0], vals[1]), fmaxf(vals[2], vals[3]));
    red[tid] = mx;
    __syncthreads();
    for (int o = 128; o > 0; o >>= 1) {
        if (tid < o) red[tid] = fmaxf(red[tid], red[tid + o]);
        __syncthreads();
    }
    float rmax = red[0];
    __syncthreads();
    float exs[4]; float psum = 0.f;
    for (int i = 0; i < 4; ++i) { exs[i] = __expf(vals[i] - rmax); psum += exs[i]; }
    red[tid] = psum;
    __syncthreads();
    for (int o = 128; o > 0; o >>= 1) {
        if (tid < o) red[tid] += red[tid + o];
        __syncthreads();
    }
    float inv = 1.f / red[0];
    for (int i = 0; i < 4; ++i) {
        int t = tid + 256 * i;
        atts_out[((size_t)s * B_ + b) * 1024 + t] = exs[i] * inv;
    }
}

// context[b][d] = sum_t att[t] * L[b][t][d] ; writes ctxT[d][b]
__global__ __launch_bounds__(256) void k_ctx(
        int s, int useBf,
        const unsigned short* __restrict__ Lbf, const float* __restrict__ Lf,
        const float* __restrict__ atts_out, float* __restrict__ ctxT) {
    __shared__ float red[4][128];
    int tid = threadIdx.x;
    int b = blockIdx.x >> 2;
    int d0 = (blockIdx.x & 3) * 128;
    int lane = tid & 63, q = tid >> 6;
    const float* att = atts_out + ((size_t)s * B_ + b) * 1024;
    float a0 = 0.f, a1 = 0.f;
    int dl = 2 * lane;
    if (useBf) {
        const unsigned short* Lb = Lbf + ((size_t)b * 1024) * 512 + d0 + dl;
#pragma unroll 4
        for (int tt = 0; tt < 256; ++tt) {
            int t = q * 256 + tt;
            float w = att[t];
            unsigned int v = *(const unsigned int*)(Lb + (size_t)t * 512);
            a0 = fmaf(w, bf2f((unsigned short)(v & 0xffff)), a0);
            a1 = fmaf(w, bf2f((unsigned short)(v >> 16)), a1);
        }
    } else {
        const float* Lp = Lf + ((size_t)b * 1024) * 512 + d0 + dl;
#pragma unroll 4
        for (int tt = 0; tt < 256; ++tt) {
            int t = q * 256 + tt;
            float w = att[t];
            float2 v = *(const float2*)(Lp + (size_t)t * 512);
            a0 = fmaf(w, v.x, a0);
            a1 = fmaf(w, v.y, a1);
        }
    }
    red[q][dl] = a0;
    red[q][dl + 1] = a1;
    __syncthreads();
    if (tid < 128) {
        float sum = red[0][tid] + red[1][tid] + red[2][tid] + red[3][tid];
        ctxT[(d0 + tid) * 64 + b] = sum;
    }
}

extern "C" void kernel_launch(void* const* d_in, const int* in_sizes, int n_in,
                              void* d_out, int out_size, void* d_ws, size_t ws_size,
                              hipStream_t stream) {
    const float* Lf   = (const float*)d_in[0];
    const float* gt   = (const float*)d_in[1];
    const float* phiw = (const float*)d_in[2];
    const float* phib = (const float*)d_in[3];
    const float* psiw = (const float*)d_in[4];
    const float* psib = (const float*)d_in[5];
    const float* wih0 = (const float*)d_in[6];
    const float* whh0 = (const float*)d_in[7];
    const float* bih0 = (const float*)d_in[8];
    const float* bhh0 = (const float*)d_in[9];
    const float* wih1 = (const float*)d_in[10];
    const float* whh1 = (const float*)d_in[11];
    const float* bih1 = (const float*)d_in[12];
    const float* bhh1 = (const float*)d_in[13];
    const float* charw = (const float*)d_in[14];
    const float* charb = (const float*)d_in[15];

    float* preds = (float*)d_out;
    float* atts  = (float*)d_out + (size_t)SS * B_ * CC;

    char* ws = (char*)d_ws;
    size_t off = 0;
    auto alloc = [&](size_t bytes) { size_t o = off; off = (off + bytes + 255) & ~(size_t)255; return o; };
    unsigned short* clT = (unsigned short*)(ws + alloc((size_t)B_ * M_ * T_ * 2));
    float* gtT  = (float*)(ws + alloc((size_t)SS * CC * 64 * 4));
    float* h0A  = (float*)(ws + alloc(H_ * B_ * 4));
    float* h0B  = (float*)(ws + alloc(H_ * B_ * 4));
    float* c0   = (float*)(ws + alloc(H_ * B_ * 4));
    float* h1A  = (float*)(ws + alloc(H_ * B_ * 4));
    float* h1B  = (float*)(ws + alloc(H_ * B_ * 4));
    float* c1   = (float*)(ws + alloc(H_ * B_ * 4));
    float* ctxT = (float*)(ws + alloc(H_ * B_ * 4));
    float* energy = (float*)(ws + alloc(B_ * T_ * 4));
    size_t baseNeed = off;
    size_t lbfBytes = (size_t)B_ * T_ * D_ * 2;
    int useBf = (baseNeed + lbfBytes + 256 <= ws_size) ? 1 : 0;
    unsigned short* Lbf = (unsigned short*)(ws + (useBf ? alloc(lbfBytes) : 0));

    k_init<<<128, 256, 0, stream>>>(Lf, h0A, h0B, c0, h1A, h1B, c1, ctxT);
    k_gtt<<<64, 256, 0, stream>>>(gt, gtT);
    if (useBf) k_conv<<<2048, 256, 0, stream>>>(Lf, Lbf, (B_ * T_ * D_) / 4);
    k_gemm<<<4096, 256, 0, stream>>>(Lf, psiw, psib, clT);

    float* h0c = h0A; float* h0n = h0B;
    float* h1c = h1A; float* h1n = h1B;
    for (int s = 0; s < SS; ++s) {
        int mode = (s == 0) ? 0 : 1;
        int grid = (s == 0) ? 256 : 320;
        k_dec<<<grid, 256, 0, stream>>>(mode, s, s - 1, gtT, wih0, whh0, bih0, bhh0,
                                        charw, charb, h0c, h0n, c0, h1c, ctxT, preds);
        k_lstm1<<<256, 256, 0, stream>>>(wih1, whh1, bih1, bhh1, h0n, h1c, h1n, c1);
        k_energy<<<128, 256, 0, stream>>>(phiw, phib, h1n, clT, energy);
        k_att<<<64, 256, 0, stream>>>(s, energy, atts);
        k_ctx<<<256, 256, 0, stream>>>(s, useBf, Lbf, Lf, atts, ctxT);
        float* tmp = h0c; h0c = h0n; h0n = tmp;
        tmp = h1c; h1c = h1n; h1n = tmp;
    }
    // final step's char-pred
    k_dec<<<64, 256, 0, stream>>>(2, SS, SS - 1, gtT, wih0, whh0, bih0, bhh0,
                                  charw, charb, h0c, h0n, c0, h1c, ctxT, preds);
}